// Round 5
// baseline (644.973 us; speedup 1.0000x reference)
//
#include <hip/hip_runtime.h>

typedef unsigned short ushort_t;
typedef unsigned int uint_t;
typedef __attribute__((ext_vector_type(8))) short bf16x8;
typedef __attribute__((ext_vector_type(4))) float floatx4;

#define ZDIM 32
#define KDIM 4
#define HDIM 128
#define B_TOTAL 32768
#define TB 32

// ws layout (ushort element offsets): Wd hi/lo reordered [k][n][c], Wsm hi/lo [m][n][c]
#define WS_WDH 0
#define WS_WDL 524288
#define WS_SMH 1048576
#define WS_SML 1097728

// LDS layout (byte offsets). D is fp16: [batch][i][j] at batch*1092 + i*34 + j
// (ushort units).
#define D_ROW   34
#define D_BP    1092
#define SH_D_OFF  0          // ushort[32][1092] = 69888 B
#define AUX_PITCH 132
#define SH_AUX_OFF 0         // float [3][32][132] = 50688 B (pre-loop, aliases D)
#define SH_HH_OFF 50688      // ushort [32][136] = 8704 B (pre-loop, aliases D)
#define SH_HL_OFF 59392      // ushort [32][136] = 8704 B (ends 68096 <= 69888)
#define SH_Z_OFF  69888      // float [32][36] = 4608 B
#define SH_T_OFF  74496      // float [32][36] = 4608 B
#define LDS_BYTES 79104      // x2 = 158208 <= 160 KiB -> 2 WG/CU

__device__ __forceinline__ ushort_t f2bf(float f) {
    uint_t u = __builtin_bit_cast(uint_t, f);
    u += 0x7FFFu + ((u >> 16) & 1u);
    return (ushort_t)(u >> 16);
}
__device__ __forceinline__ float bf2f(ushort_t s) {
    return __builtin_bit_cast(float, ((uint_t)s) << 16);
}
__device__ __forceinline__ void split1(float x, ushort_t& hi, ushort_t& lo) {
    hi = f2bf(x);
    lo = f2bf(x - bf2f(hi));
}
__device__ __forceinline__ void split4(float4 v, ushort4& hi, ushort4& lo) {
    split1(v.x, hi.x, lo.x); split1(v.y, hi.y, lo.y);
    split1(v.z, hi.z, lo.z); split1(v.w, hi.w, lo.w);
}
__device__ __forceinline__ float fast_tanh(float x) {
    float e = __expf(2.0f * x);
    return 1.0f - 2.0f / (e + 1.0f);
}
__device__ __forceinline__ float f16lo(uint_t v) {
    return (float)__builtin_bit_cast(_Float16, (ushort_t)(v & 0xFFFFu));
}
__device__ __forceinline__ float f16hi(uint_t v) {
    return (float)__builtin_bit_cast(_Float16, (ushort_t)(v >> 16));
}

// ---------------------------------------------------------------------------
// Kernel 1: split Wd (reordered per-k-slice) and Wd1/Wd2/Wb into bf16 hi/lo.
// ---------------------------------------------------------------------------
__global__ __launch_bounds__(256) void convert_kernel(
    const float* __restrict__ Wd, const float* __restrict__ Wd1,
    const float* __restrict__ Wd2, const float* __restrict__ Wb,
    ushort_t* __restrict__ ws)
{
    int g = blockIdx.x * 256 + threadIdx.x;
    if (g < 131072) {
        int k = g >> 15;            // 32768 float4 per k-slice
        int rem = g & 32767;
        int n = rem >> 5;           // n = i*32+j
        int c4 = rem & 31;
        float4 v = *((const float4*)Wd + (size_t)(4 * n + k) * 32 + c4);
        ushort4 hi, lo; split4(v, hi, lo);
        ((ushort4*)(ws + WS_WDH))[g] = hi;
        ((ushort4*)(ws + WS_WDL))[g] = lo;
    } else {
        int s = g - 131072;         // [0, 12288)
        const float* src = (s < 4096) ? Wd1 : ((s < 8192) ? Wd2 : Wb);
        int r = s & 4095;
        float4 v = ((const float4*)src)[r];
        ushort4 hi, lo; split4(v, hi, lo);
        ((ushort4*)(ws + WS_SMH))[s] = hi;
        ((ushort4*)(ws + WS_SML))[s] = lo;
    }
}

// ---------------------------------------------------------------------------
// Kernel 2: fused split-bf16 encoder GEMMs (fp32-accurate) + K-step flow.
// 512 threads, 2 WGs/CU. Each wave owns ONE 16-batch row-half (rh = w&1):
// fragment footprint = 32 VGPRs, so the 4-waves/EU VGPR budget (128) holds
// without spill (round-4 regression: 64-VGPR cap -> 700 MB scratch traffic).
// ---------------------------------------------------------------------------
__global__ __launch_bounds__(512, 4) void sylv_kernel(
    const ushort_t* __restrict__ wsb,
    const float* __restrict__ hglob,
    const float* __restrict__ z0,
    const float* __restrict__ bd,
    const float* __restrict__ bd1,
    const float* __restrict__ bd2,
    const float* __restrict__ bb,
    float* __restrict__ out)
{
    extern __shared__ char smem[];
    _Float16* Dh     = (_Float16*)(smem + SH_D_OFF);
    float*    sh_aux = (float*)(smem + SH_AUX_OFF);
    ushort_t* sh_hh  = (ushort_t*)(smem + SH_HH_OFF);
    ushort_t* sh_hl  = (ushort_t*)(smem + SH_HL_OFF);
    float*    sh_z   = (float*)(smem + SH_Z_OFF);
    float*    sh_t   = (float*)(smem + SH_T_OFF);

    const int t   = threadIdx.x;
    const int bg0 = blockIdx.x * TB;
    const int lane = t & 63, w = t >> 6;
    const int l15 = lane & 15, l4 = lane >> 4;
    const int rh = w & 1;           // row-half (batches rh*16 .. rh*16+15)
    const int cg = w >> 1;          // column group (256 cols each)
    // flow mapping: 16 contiguous lanes (one quarter-wave) own one batch fb.
    const int j2 = t & 15;
    const int bq = (t >> 4) & 3;
    const int fb = (w & 1) | (bq << 1) | ((w >> 1) << 3);

    // ---- stage h (fp32 -> bf16 hi/lo in LDS) and z0 ----
    {
        const float4* hsrc = (const float4*)(hglob + (size_t)bg0 * HDIM);
        #pragma unroll
        for (int it = 0; it < 2; ++it) {
            int c = t + it * 512;       // 1024 float4 chunks
            int row = c >> 5, col4 = c & 31;
            float4 v = hsrc[c];
            ushort4 hi, lo; split4(v, hi, lo);
            *(ushort4*)(sh_hh + row * 136 + col4 * 4) = hi;
            *(ushort4*)(sh_hl + row * 136 + col4 * 4) = lo;
        }
        int zb = t >> 4, zc = t & 15;
        float2 zv = *(const float2*)(z0 + (size_t)(bg0 + zb) * ZDIM + zc * 2);
        *(float2*)(sh_z + zb * 36 + zc * 2) = zv;
    }
    __syncthreads();

    // ---- A fragments (hi and lo) for THIS wave's row-half only ----
    bf16x8 ahi[4], alo[4];
    #pragma unroll
    for (int kc = 0; kc < 4; ++kc) {
        ahi[kc] = *(const bf16x8*)(sh_hh + (rh * 16 + l15) * 136 + kc * 32 + l4 * 8);
        alo[kc] = *(const bf16x8*)(sh_hl + (rh * 16 + l15) * 136 + kc * 32 + l4 * 8);
    }

    // ---- small GEMMs (3-pass split): d1, d2, bpre -> aux[m][batch][n] ----
    // 48 jobs = 3 matrices x 2 row-halves x 8 col-tiles; wave does 6 for its rh.
    #pragma unroll
    for (int pi = 0; pi < 6; ++pi) {
        int p = cg * 6 + pi;            // [0,24)
        int m_i = p >> 3, nt = p & 7, n = nt * 16 + l15;
        const ushort_t* wph = wsb + WS_SMH + (size_t)(m_i * 128 + n) * 128 + l4 * 8;
        const ushort_t* wpl = wsb + WS_SML + (size_t)(m_i * 128 + n) * 128 + l4 * 8;
        floatx4 a0 = {0.f, 0.f, 0.f, 0.f};
        #pragma unroll
        for (int kc = 0; kc < 4; ++kc) {
            bf16x8 bh = *(const bf16x8*)(wph + kc * 32);
            bf16x8 bl = *(const bf16x8*)(wpl + kc * 32);
            a0 = __builtin_amdgcn_mfma_f32_16x16x32_bf16(ahi[kc], bh, a0, 0, 0, 0);
            a0 = __builtin_amdgcn_mfma_f32_16x16x32_bf16(alo[kc], bh, a0, 0, 0, 0);
            a0 = __builtin_amdgcn_mfma_f32_16x16x32_bf16(ahi[kc], bl, a0, 0, 0, 0);
        }
        const float* bv = (m_i == 0) ? bd1 : ((m_i == 1) ? bd2 : bb);
        float bias = bv[n];
        float* ap = sh_aux + m_i * (32 * AUX_PITCH) + n;
        #pragma unroll
        for (int r = 0; r < 4; ++r) {
            float v0 = a0[r] + bias;
            if (m_i < 2) v0 = fast_tanh(v0);
            ap[(rh * 16 + l4 * 4 + r) * AUX_PITCH] = v0;
        }
    }
    __syncthreads();

    // ---- aux -> registers (24 floats/thread), then free the D region ----
    float4 d1a = *(const float4*)(sh_aux + 0 * (32 * AUX_PITCH) + fb * AUX_PITCH + j2 * 4);
    float4 d2a = *(const float4*)(sh_aux + 1 * (32 * AUX_PITCH) + fb * AUX_PITCH + j2 * 4);
    float4 bpa = *(const float4*)(sh_aux + 2 * (32 * AUX_PITCH) + fb * AUX_PITCH + j2 * 4);
    float4 d1b = *(const float4*)(sh_aux + 0 * (32 * AUX_PITCH) + fb * AUX_PITCH + (j2 + 16) * 4);
    float4 d2b = *(const float4*)(sh_aux + 1 * (32 * AUX_PITCH) + fb * AUX_PITCH + (j2 + 16) * 4);
    float4 bpb = *(const float4*)(sh_aux + 2 * (32 * AUX_PITCH) + fb * AUX_PITCH + (j2 + 16) * 4);
    __syncthreads();

    float ld_acc = 0.f;
    const _Float16* Db  = Dh + fb * D_BP;
    const uint_t*   Dbw = (const uint_t*)Db;

    #pragma unroll
    for (int kk = 0; kk < KDIM; ++kk) {
        // ---- GEMM: D_k[b][n] = h@Wd_k^T + bd, fp32 via 3-pass split ----
        const size_t kbase = (size_t)(kk * 1024) * 128;
        #pragma unroll
        for (int g = 0; g < 8; ++g) {
            int nc0 = cg * 256 + g * 32 + l15;
            int nc1 = nc0 + 16;
            const ushort_t* w0h = wsb + WS_WDH + kbase + (size_t)nc0 * 128 + l4 * 8;
            const ushort_t* w0l = wsb + WS_WDL + kbase + (size_t)nc0 * 128 + l4 * 8;
            const ushort_t* w1h = w0h + 16 * 128;
            const ushort_t* w1l = w0l + 16 * 128;
            floatx4 a0 = {0.f,0.f,0.f,0.f}, a1 = {0.f,0.f,0.f,0.f};
            #pragma unroll
            for (int kc = 0; kc < 4; ++kc) {
                bf16x8 b0h = *(const bf16x8*)(w0h + kc * 32);
                bf16x8 b0l = *(const bf16x8*)(w0l + kc * 32);
                bf16x8 b1h = *(const bf16x8*)(w1h + kc * 32);
                bf16x8 b1l = *(const bf16x8*)(w1l + kc * 32);
                a0 = __builtin_amdgcn_mfma_f32_16x16x32_bf16(ahi[kc], b0h, a0, 0, 0, 0);
                a0 = __builtin_amdgcn_mfma_f32_16x16x32_bf16(alo[kc], b0h, a0, 0, 0, 0);
                a0 = __builtin_amdgcn_mfma_f32_16x16x32_bf16(ahi[kc], b0l, a0, 0, 0, 0);
                a1 = __builtin_amdgcn_mfma_f32_16x16x32_bf16(ahi[kc], b1h, a1, 0, 0, 0);
                a1 = __builtin_amdgcn_mfma_f32_16x16x32_bf16(alo[kc], b1h, a1, 0, 0, 0);
                a1 = __builtin_amdgcn_mfma_f32_16x16x32_bf16(ahi[kc], b1l, a1, 0, 0, 0);
            }
            int ii = nc0 >> 5;
            int base0 = ii * D_ROW + (nc0 & 31);
            int base1 = base0 + 16;
            float bias0 = bd[4 * nc0 + kk];
            float bias1 = bd[4 * nc1 + kk];
            #pragma unroll
            for (int r = 0; r < 4; ++r) {
                Dh[(rh * 16 + l4 * 4 + r) * D_BP + base0] = (_Float16)(a0[r] + bias0);
                Dh[(rh * 16 + l4 * 4 + r) * D_BP + base1] = (_Float16)(a1[r] + bias1);
            }
        }
        __syncthreads();

        // ---- pre[j] = b[j] + z_per[j]*d2[j] + sum_{i>j} z_per[i]*D[i,j] ----
        const bool flip = (kk & 1) != 0;
        const int zj0 = flip ? (31 - j2) : j2;
        const int zj1 = flip ? (15 - j2) : (j2 + 16);
        float s0 = bpa[kk] + sh_z[fb * 36 + zj0] * d2a[kk];
        float s1 = bpb[kk] + sh_z[fb * 36 + zj1] * d2b[kk];
        #pragma unroll
        for (int i = 1; i <= 15; ++i) {       // masked vs j2
            float zi = sh_z[fb * 36 + (flip ? (31 - i) : i)];
            float dd = (float)Db[i * D_ROW + j2];
            s0 = fmaf(dd, (i > j2) ? zi : 0.f, s0);
        }
        #pragma unroll
        for (int i = 16; i < 32; ++i) {       // i > j2 always; s1 masked
            float zi = sh_z[fb * 36 + (flip ? (31 - i) : i)];
            s0 = fmaf((float)Db[i * D_ROW + j2], zi, s0);
            if (i >= 17)
                s1 = fmaf((float)Db[i * D_ROW + j2 + 16], (i > j2 + 16) ? zi : 0.f, s1);
        }
        float t0 = fast_tanh(s0), t1 = fast_tanh(s1);
        sh_t[fb * 36 + j2] = t0;
        sh_t[fb * 36 + j2 + 16] = t1;
        float dj0 = (1.f - t0 * t0) * (d1a[kk] * d2a[kk]) + 1.f;
        float dj1 = (1.f - t1 * t1) * (d1b[kk] * d2b[kk]) + 1.f;
        ld_acc += __logf(fabsf(dj0)) + __logf(fabsf(dj1));
        // no barrier: t/z exchange is within the 16-lane fb group (same wave)

        // ---- dz[p] = t[p]*d1[p] + sum_{j>p} t[j]*D[p,j]; z update ----
        float dz0 = t0 * d1a[kk];             // p = j2
        float dz1 = t1 * d1b[kk];             // p = j2+16
        const uint_t* r0 = Dbw + j2 * 17;     // D_ROW/2 words
        const uint_t* r1 = Dbw + (j2 + 16) * 17;
        #pragma unroll
        for (int w2 = 0; w2 < 8; ++w2) {      // j in [0,16): only dz0, masked
            uint_t v = r0[w2];
            int j0 = 2 * w2;
            float tl = sh_t[fb * 36 + j0];
            float th = sh_t[fb * 36 + j0 + 1];
            dz0 = fmaf(f16lo(v), (j0 > j2) ? tl : 0.f, dz0);
            dz0 = fmaf(f16hi(v), (j0 + 1 > j2) ? th : 0.f, dz0);
        }
        #pragma unroll
        for (int w2 = 8; w2 < 16; ++w2) {     // j in [16,32): dz0 unmasked, dz1 masked
            uint_t v0 = r0[w2];
            uint_t v1 = r1[w2];
            int j0 = 2 * w2;
            float tl = sh_t[fb * 36 + j0];
            float th = sh_t[fb * 36 + j0 + 1];
            dz0 = fmaf(f16lo(v0), tl, dz0);
            dz0 = fmaf(f16hi(v0), th, dz0);
            dz1 = fmaf(f16lo(v1), (j0 > j2 + 16) ? tl : 0.f, dz1);
            dz1 = fmaf(f16hi(v1), (j0 + 1 > j2 + 16) ? th : 0.f, dz1);
        }
        sh_z[fb * 36 + zj0] += dz0;
        sh_z[fb * 36 + zj1] += dz1;
        __syncthreads();
    }

    // ---- epilogue: write z and log_det_j ----
    {
        int zb = t >> 4, zc = t & 15;
        float2 zv = *(const float2*)(sh_z + zb * 36 + zc * 2);
        *(float2*)(out + (size_t)(bg0 + zb) * ZDIM + zc * 2) = zv;
        float v = ld_acc;
        v += __shfl_xor(v, 1, 16);
        v += __shfl_xor(v, 2, 16);
        v += __shfl_xor(v, 4, 16);
        v += __shfl_xor(v, 8, 16);
        if (j2 == 0) out[(size_t)B_TOTAL * ZDIM + bg0 + fb] = v;
    }
}

extern "C" void kernel_launch(void* const* d_in, const int* in_sizes, int n_in,
                              void* d_out, int out_size, void* d_ws, size_t ws_size,
                              hipStream_t stream) {
    const float* z0  = (const float*)d_in[0];
    const float* h   = (const float*)d_in[1];
    const float* Wd  = (const float*)d_in[2];
    const float* bd  = (const float*)d_in[3];
    const float* Wd1 = (const float*)d_in[4];
    const float* bd1 = (const float*)d_in[5];
    const float* Wd2 = (const float*)d_in[6];
    const float* bd2 = (const float*)d_in[7];
    const float* Wb  = (const float*)d_in[8];
    const float* bb  = (const float*)d_in[9];
    ushort_t* ws = (ushort_t*)d_ws;
    float* out = (float*)d_out;

    convert_kernel<<<560, 256, 0, stream>>>(Wd, Wd1, Wd2, Wb, ws);

    (void)hipFuncSetAttribute((const void*)sylv_kernel,
                              hipFuncAttributeMaxDynamicSharedMemorySize, LDS_BYTES);
    sylv_kernel<<<B_TOTAL / TB, 512, LDS_BYTES, stream>>>(ws, h, z0, bd, bd1, bd2, bb, out);
}

// Round 6
// 613.907 us; speedup vs baseline: 1.0506x; 1.0506x over previous
//
#include <hip/hip_runtime.h>

typedef unsigned short ushort_t;
typedef unsigned int uint_t;
typedef __attribute__((ext_vector_type(8))) short bf16x8;
typedef __attribute__((ext_vector_type(4))) float floatx4;

#define ZDIM 32
#define KDIM 4
#define HDIM 128
#define B_TOTAL 32768
#define TB 32

// ws layout (ushort element offsets): Wd hi/lo reordered [k][n][c], Wsm hi/lo [m][n][c]
#define WS_WDH 0
#define WS_WDL 524288
#define WS_SMH 1048576
#define WS_SML 1097728

// LDS layout (byte offsets). D is fp16: [batch][i][j] at batch*1092 + i*34 + j
// (ushort units).
#define D_ROW   34
#define D_BP    1092
#define SH_D_OFF  0          // ushort[32][1092] = 69888 B
#define AUX_PITCH 132
#define SH_AUX_OFF 0         // float [3][32][132] = 50688 B (pre-loop, aliases D)
#define SH_HH_OFF 50688      // ushort [32][136] = 8704 B (pre-loop, aliases D)
#define SH_HL_OFF 59392      // ushort [32][136] = 8704 B (ends 68096 <= 69888)
#define SH_Z_OFF  69888      // float [32][36] = 4608 B
#define SH_T_OFF  74496      // float [32][36] = 4608 B
#define LDS_BYTES 79104      // x2 = 158208 <= 160 KiB -> 2 WG/CU via LDS limit

__device__ __forceinline__ ushort_t f2bf(float f) {
    uint_t u = __builtin_bit_cast(uint_t, f);
    u += 0x7FFFu + ((u >> 16) & 1u);
    return (ushort_t)(u >> 16);
}
__device__ __forceinline__ float bf2f(ushort_t s) {
    return __builtin_bit_cast(float, ((uint_t)s) << 16);
}
__device__ __forceinline__ void split1(float x, ushort_t& hi, ushort_t& lo) {
    hi = f2bf(x);
    lo = f2bf(x - bf2f(hi));
}
__device__ __forceinline__ void split4(float4 v, ushort4& hi, ushort4& lo) {
    split1(v.x, hi.x, lo.x); split1(v.y, hi.y, lo.y);
    split1(v.z, hi.z, lo.z); split1(v.w, hi.w, lo.w);
}
__device__ __forceinline__ float fast_tanh(float x) {
    float e = __expf(2.0f * x);
    return 1.0f - 2.0f / (e + 1.0f);
}
__device__ __forceinline__ float f16lo(uint_t v) {
    return (float)__builtin_bit_cast(_Float16, (ushort_t)(v & 0xFFFFu));
}
__device__ __forceinline__ float f16hi(uint_t v) {
    return (float)__builtin_bit_cast(_Float16, (ushort_t)(v >> 16));
}

// ---------------------------------------------------------------------------
// Kernel 1: split Wd (reordered per-k-slice) and Wd1/Wd2/Wb into bf16 hi/lo.
// ---------------------------------------------------------------------------
__global__ __launch_bounds__(256) void convert_kernel(
    const float* __restrict__ Wd, const float* __restrict__ Wd1,
    const float* __restrict__ Wd2, const float* __restrict__ Wb,
    ushort_t* __restrict__ ws)
{
    int g = blockIdx.x * 256 + threadIdx.x;
    if (g < 131072) {
        int k = g >> 15;            // 32768 float4 per k-slice
        int rem = g & 32767;
        int n = rem >> 5;           // n = i*32+j
        int c4 = rem & 31;
        float4 v = *((const float4*)Wd + (size_t)(4 * n + k) * 32 + c4);
        ushort4 hi, lo; split4(v, hi, lo);
        ((ushort4*)(ws + WS_WDH))[g] = hi;
        ((ushort4*)(ws + WS_WDL))[g] = lo;
    } else {
        int s = g - 131072;         // [0, 12288)
        const float* src = (s < 4096) ? Wd1 : ((s < 8192) ? Wd2 : Wb);
        int r = s & 4095;
        float4 v = ((const float4*)src)[r];
        ushort4 hi, lo; split4(v, hi, lo);
        ((ushort4*)(ws + WS_SMH))[s] = hi;
        ((ushort4*)(ws + WS_SML))[s] = lo;
    }
}

// ---------------------------------------------------------------------------
// Kernel 2: fused split-bf16 encoder GEMMs (fp32-accurate) + K-step flow.
// 512 threads. Occupancy plan: LDS 79 KB -> 2 WGs/CU; __launch_bounds__(512,2)
// caps VGPRs at 128 (empirical hipcc rule: cap = 256/min_waves) which both
// fits this kernel WITHOUT spill (round-4/5 lesson: a 64-cap spills ~500 MB)
// and allows 16 waves/CU at the hardware level (m69: 128-VGPR waves).
// Each wave owns ONE 16-batch row-half (rh) -> fragment footprint 32 VGPRs.
// ---------------------------------------------------------------------------
__global__ __launch_bounds__(512, 2) void sylv_kernel(
    const ushort_t* __restrict__ wsb,
    const float* __restrict__ hglob,
    const float* __restrict__ z0,
    const float* __restrict__ bd,
    const float* __restrict__ bd1,
    const float* __restrict__ bd2,
    const float* __restrict__ bb,
    float* __restrict__ out)
{
    extern __shared__ char smem[];
    _Float16* Dh     = (_Float16*)(smem + SH_D_OFF);
    float*    sh_aux = (float*)(smem + SH_AUX_OFF);
    ushort_t* sh_hh  = (ushort_t*)(smem + SH_HH_OFF);
    ushort_t* sh_hl  = (ushort_t*)(smem + SH_HL_OFF);
    float*    sh_z   = (float*)(smem + SH_Z_OFF);
    float*    sh_t   = (float*)(smem + SH_T_OFF);

    const int t   = threadIdx.x;
    const int bg0 = blockIdx.x * TB;
    const int lane = t & 63, w = t >> 6;
    const int l15 = lane & 15, l4 = lane >> 4;
    const int rh = w & 1;           // row-half (batches rh*16 .. rh*16+15)
    const int cg = w >> 1;          // column group (256 cols each)
    // flow mapping: 16 contiguous lanes (one quarter-wave) own one batch fb.
    const int j2 = t & 15;
    const int bq = (t >> 4) & 3;
    const int fb = (w & 1) | (bq << 1) | ((w >> 1) << 3);

    // ---- stage h (fp32 -> bf16 hi/lo in LDS) and z0 ----
    {
        const float4* hsrc = (const float4*)(hglob + (size_t)bg0 * HDIM);
        #pragma unroll
        for (int it = 0; it < 2; ++it) {
            int c = t + it * 512;       // 1024 float4 chunks
            int row = c >> 5, col4 = c & 31;
            float4 v = hsrc[c];
            ushort4 hi, lo; split4(v, hi, lo);
            *(ushort4*)(sh_hh + row * 136 + col4 * 4) = hi;
            *(ushort4*)(sh_hl + row * 136 + col4 * 4) = lo;
        }
        int zb = t >> 4, zc = t & 15;
        float2 zv = *(const float2*)(z0 + (size_t)(bg0 + zb) * ZDIM + zc * 2);
        *(float2*)(sh_z + zb * 36 + zc * 2) = zv;
    }
    __syncthreads();

    // ---- A fragments (hi and lo) for THIS wave's row-half only ----
    bf16x8 ahi[4], alo[4];
    #pragma unroll
    for (int kc = 0; kc < 4; ++kc) {
        ahi[kc] = *(const bf16x8*)(sh_hh + (rh * 16 + l15) * 136 + kc * 32 + l4 * 8);
        alo[kc] = *(const bf16x8*)(sh_hl + (rh * 16 + l15) * 136 + kc * 32 + l4 * 8);
    }

    // ---- small GEMMs (3-pass split): d1, d2, bpre -> aux[m][batch][n] ----
    // 48 jobs = 3 matrices x 2 row-halves x 8 col-tiles; wave does 6 for its rh.
    #pragma unroll
    for (int pi = 0; pi < 6; ++pi) {
        int p = cg * 6 + pi;            // [0,24)
        int m_i = p >> 3, nt = p & 7, n = nt * 16 + l15;
        const ushort_t* wph = wsb + WS_SMH + (size_t)(m_i * 128 + n) * 128 + l4 * 8;
        const ushort_t* wpl = wsb + WS_SML + (size_t)(m_i * 128 + n) * 128 + l4 * 8;
        floatx4 a0 = {0.f, 0.f, 0.f, 0.f};
        #pragma unroll
        for (int kc = 0; kc < 4; ++kc) {
            bf16x8 bh = *(const bf16x8*)(wph + kc * 32);
            bf16x8 bl = *(const bf16x8*)(wpl + kc * 32);
            a0 = __builtin_amdgcn_mfma_f32_16x16x32_bf16(ahi[kc], bh, a0, 0, 0, 0);
            a0 = __builtin_amdgcn_mfma_f32_16x16x32_bf16(alo[kc], bh, a0, 0, 0, 0);
            a0 = __builtin_amdgcn_mfma_f32_16x16x32_bf16(ahi[kc], bl, a0, 0, 0, 0);
        }
        const float* bv = (m_i == 0) ? bd1 : ((m_i == 1) ? bd2 : bb);
        float bias = bv[n];
        float* ap = sh_aux + m_i * (32 * AUX_PITCH) + n;
        #pragma unroll
        for (int r = 0; r < 4; ++r) {
            float v0 = a0[r] + bias;
            if (m_i < 2) v0 = fast_tanh(v0);
            ap[(rh * 16 + l4 * 4 + r) * AUX_PITCH] = v0;
        }
    }
    __syncthreads();

    // ---- aux -> registers (24 floats/thread), then free the D region ----
    float4 d1a = *(const float4*)(sh_aux + 0 * (32 * AUX_PITCH) + fb * AUX_PITCH + j2 * 4);
    float4 d2a = *(const float4*)(sh_aux + 1 * (32 * AUX_PITCH) + fb * AUX_PITCH + j2 * 4);
    float4 bpa = *(const float4*)(sh_aux + 2 * (32 * AUX_PITCH) + fb * AUX_PITCH + j2 * 4);
    float4 d1b = *(const float4*)(sh_aux + 0 * (32 * AUX_PITCH) + fb * AUX_PITCH + (j2 + 16) * 4);
    float4 d2b = *(const float4*)(sh_aux + 1 * (32 * AUX_PITCH) + fb * AUX_PITCH + (j2 + 16) * 4);
    float4 bpb = *(const float4*)(sh_aux + 2 * (32 * AUX_PITCH) + fb * AUX_PITCH + (j2 + 16) * 4);
    __syncthreads();

    float ld_acc = 0.f;
    const _Float16* Db  = Dh + fb * D_BP;
    const uint_t*   Dbw = (const uint_t*)Db;

    #pragma unroll
    for (int kk = 0; kk < KDIM; ++kk) {
        // ---- GEMM: D_k[b][n] = h@Wd_k^T + bd, fp32 via 3-pass split ----
        const size_t kbase = (size_t)(kk * 1024) * 128;
        #pragma unroll
        for (int g = 0; g < 8; ++g) {
            int nc0 = cg * 256 + g * 32 + l15;
            int nc1 = nc0 + 16;
            const ushort_t* w0h = wsb + WS_WDH + kbase + (size_t)nc0 * 128 + l4 * 8;
            const ushort_t* w0l = wsb + WS_WDL + kbase + (size_t)nc0 * 128 + l4 * 8;
            const ushort_t* w1h = w0h + 16 * 128;
            const ushort_t* w1l = w0l + 16 * 128;
            floatx4 a0 = {0.f,0.f,0.f,0.f}, a1 = {0.f,0.f,0.f,0.f};
            #pragma unroll
            for (int kc = 0; kc < 4; ++kc) {
                bf16x8 b0h = *(const bf16x8*)(w0h + kc * 32);
                bf16x8 b0l = *(const bf16x8*)(w0l + kc * 32);
                bf16x8 b1h = *(const bf16x8*)(w1h + kc * 32);
                bf16x8 b1l = *(const bf16x8*)(w1l + kc * 32);
                a0 = __builtin_amdgcn_mfma_f32_16x16x32_bf16(ahi[kc], b0h, a0, 0, 0, 0);
                a0 = __builtin_amdgcn_mfma_f32_16x16x32_bf16(alo[kc], b0h, a0, 0, 0, 0);
                a0 = __builtin_amdgcn_mfma_f32_16x16x32_bf16(ahi[kc], b0l, a0, 0, 0, 0);
                a1 = __builtin_amdgcn_mfma_f32_16x16x32_bf16(ahi[kc], b1h, a1, 0, 0, 0);
                a1 = __builtin_amdgcn_mfma_f32_16x16x32_bf16(alo[kc], b1h, a1, 0, 0, 0);
                a1 = __builtin_amdgcn_mfma_f32_16x16x32_bf16(ahi[kc], b1l, a1, 0, 0, 0);
            }
            int ii = nc0 >> 5;
            int base0 = ii * D_ROW + (nc0 & 31);
            int base1 = base0 + 16;
            float bias0 = bd[4 * nc0 + kk];
            float bias1 = bd[4 * nc1 + kk];
            #pragma unroll
            for (int r = 0; r < 4; ++r) {
                Dh[(rh * 16 + l4 * 4 + r) * D_BP + base0] = (_Float16)(a0[r] + bias0);
                Dh[(rh * 16 + l4 * 4 + r) * D_BP + base1] = (_Float16)(a1[r] + bias1);
            }
        }
        __syncthreads();

        // ---- pre[j] = b[j] + z_per[j]*d2[j] + sum_{i>j} z_per[i]*D[i,j] ----
        const bool flip = (kk & 1) != 0;
        const int zj0 = flip ? (31 - j2) : j2;
        const int zj1 = flip ? (15 - j2) : (j2 + 16);
        float s0 = bpa[kk] + sh_z[fb * 36 + zj0] * d2a[kk];
        float s1 = bpb[kk] + sh_z[fb * 36 + zj1] * d2b[kk];
        #pragma unroll
        for (int i = 1; i <= 15; ++i) {       // masked vs j2
            float zi = sh_z[fb * 36 + (flip ? (31 - i) : i)];
            float dd = (float)Db[i * D_ROW + j2];
            s0 = fmaf(dd, (i > j2) ? zi : 0.f, s0);
        }
        #pragma unroll
        for (int i = 16; i < 32; ++i) {       // i > j2 always; s1 masked
            float zi = sh_z[fb * 36 + (flip ? (31 - i) : i)];
            s0 = fmaf((float)Db[i * D_ROW + j2], zi, s0);
            if (i >= 17)
                s1 = fmaf((float)Db[i * D_ROW + j2 + 16], (i > j2 + 16) ? zi : 0.f, s1);
        }
        float t0 = fast_tanh(s0), t1 = fast_tanh(s1);
        sh_t[fb * 36 + j2] = t0;
        sh_t[fb * 36 + j2 + 16] = t1;
        float dj0 = (1.f - t0 * t0) * (d1a[kk] * d2a[kk]) + 1.f;
        float dj1 = (1.f - t1 * t1) * (d1b[kk] * d2b[kk]) + 1.f;
        ld_acc += __logf(fabsf(dj0)) + __logf(fabsf(dj1));
        // no barrier: t/z exchange is within the 16-lane fb group (same wave)

        // ---- dz[p] = t[p]*d1[p] + sum_{j>p} t[j]*D[p,j]; z update ----
        float dz0 = t0 * d1a[kk];             // p = j2
        float dz1 = t1 * d1b[kk];             // p = j2+16
        const uint_t* r0 = Dbw + j2 * 17;     // D_ROW/2 words
        const uint_t* r1 = Dbw + (j2 + 16) * 17;
        #pragma unroll
        for (int w2 = 0; w2 < 8; ++w2) {      // j in [0,16): only dz0, masked
            uint_t v = r0[w2];
            int j0 = 2 * w2;
            float tl = sh_t[fb * 36 + j0];
            float th = sh_t[fb * 36 + j0 + 1];
            dz0 = fmaf(f16lo(v), (j0 > j2) ? tl : 0.f, dz0);
            dz0 = fmaf(f16hi(v), (j0 + 1 > j2) ? th : 0.f, dz0);
        }
        #pragma unroll
        for (int w2 = 8; w2 < 16; ++w2) {     // j in [16,32): dz0 unmasked, dz1 masked
            uint_t v0 = r0[w2];
            uint_t v1 = r1[w2];
            int j0 = 2 * w2;
            float tl = sh_t[fb * 36 + j0];
            float th = sh_t[fb * 36 + j0 + 1];
            dz0 = fmaf(f16lo(v0), tl, dz0);
            dz0 = fmaf(f16hi(v0), th, dz0);
            dz1 = fmaf(f16lo(v1), (j0 > j2 + 16) ? tl : 0.f, dz1);
            dz1 = fmaf(f16hi(v1), (j0 + 1 > j2 + 16) ? th : 0.f, dz1);
        }
        sh_z[fb * 36 + zj0] += dz0;
        sh_z[fb * 36 + zj1] += dz1;
        __syncthreads();
    }

    // ---- epilogue: write z and log_det_j ----
    {
        int zb = t >> 4, zc = t & 15;
        float2 zv = *(const float2*)(sh_z + zb * 36 + zc * 2);
        *(float2*)(out + (size_t)(bg0 + zb) * ZDIM + zc * 2) = zv;
        float v = ld_acc;
        v += __shfl_xor(v, 1, 16);
        v += __shfl_xor(v, 2, 16);
        v += __shfl_xor(v, 4, 16);
        v += __shfl_xor(v, 8, 16);
        if (j2 == 0) out[(size_t)B_TOTAL * ZDIM + bg0 + fb] = v;
    }
}

extern "C" void kernel_launch(void* const* d_in, const int* in_sizes, int n_in,
                              void* d_out, int out_size, void* d_ws, size_t ws_size,
                              hipStream_t stream) {
    const float* z0  = (const float*)d_in[0];
    const float* h   = (const float*)d_in[1];
    const float* Wd  = (const float*)d_in[2];
    const float* bd  = (const float*)d_in[3];
    const float* Wd1 = (const float*)d_in[4];
    const float* bd1 = (const float*)d_in[5];
    const float* Wd2 = (const float*)d_in[6];
    const float* bd2 = (const float*)d_in[7];
    const float* Wb  = (const float*)d_in[8];
    const float* bb  = (const float*)d_in[9];
    ushort_t* ws = (ushort_t*)d_ws;
    float* out = (float*)d_out;

    convert_kernel<<<560, 256, 0, stream>>>(Wd, Wd1, Wd2, Wb, ws);

    (void)hipFuncSetAttribute((const void*)sylv_kernel,
                              hipFuncAttributeMaxDynamicSharedMemorySize, LDS_BYTES);
    sylv_kernel<<<B_TOTAL / TB, 512, LDS_BYTES, stream>>>(ws, h, z0, bd, bd1, bd2, bb, out);
}

// Round 7
// 375.469 us; speedup vs baseline: 1.7178x; 1.6350x over previous
//
#include <hip/hip_runtime.h>

typedef unsigned short ushort_t;
typedef unsigned int uint_t;
typedef __attribute__((ext_vector_type(8))) _Float16 f16x8;
typedef __attribute__((ext_vector_type(4))) float floatx4;

#define ZDIM 32
#define KDIM 4
#define HDIM 128
#define B_TOTAL 32768
#define TB 32

// ws layout (ushort element offsets): Wd fp16 [k][n][c], Wsm fp16 [m][n][c]
#define WS_WD16 0            // 4*1024*128 = 524288
#define WS_SM16 524288       // 3*128*128 = 49152

// LDS layout (byte offsets). D is fp16: [batch][i][j] at batch*1092 + i*34 + j
// (ushort units).
#define D_ROW   34
#define D_BP    1092
#define SH_D_OFF  0          // ushort[32][1092] = 69888 B
#define AUX_PITCH 132
#define SH_AUX_OFF 0         // float [3][32][132] = 50688 B (pre-loop, aliases D)
#define SH_H_OFF  50688      // half [32][136] = 8704 B (pre-loop, aliases D)
#define SH_Z_OFF  69888      // float [32][36] = 4608 B
#define SH_T_OFF  74496      // float [32][36] = 4608 B
#define LDS_BYTES 79104      // x2 = 158208 <= 160 KiB -> 2 WG/CU via LDS

__device__ __forceinline__ float fast_tanh(float x) {
    float e = __expf(2.0f * x);
    return 1.0f - 2.0f / (e + 1.0f);
}
__device__ __forceinline__ float f16lo(uint_t v) {
    return (float)__builtin_bit_cast(_Float16, (ushort_t)(v & 0xFFFFu));
}
__device__ __forceinline__ float f16hi(uint_t v) {
    return (float)__builtin_bit_cast(_Float16, (ushort_t)(v >> 16));
}
__device__ __forceinline__ ushort_t f2h(float x) {
    return __builtin_bit_cast(ushort_t, (_Float16)x);
}
__device__ __forceinline__ ushort4 cvt4(float4 v) {
    ushort4 o; o.x = f2h(v.x); o.y = f2h(v.y); o.z = f2h(v.z); o.w = f2h(v.w);
    return o;
}

// ---------------------------------------------------------------------------
// Kernel 1: convert Wd (reordered per-k-slice) and Wd1/Wd2/Wb to fp16.
// ---------------------------------------------------------------------------
__global__ __launch_bounds__(256) void convert_kernel(
    const float* __restrict__ Wd, const float* __restrict__ Wd1,
    const float* __restrict__ Wd2, const float* __restrict__ Wb,
    ushort_t* __restrict__ ws)
{
    int g = blockIdx.x * 256 + threadIdx.x;
    if (g < 131072) {
        int k = g >> 15;            // 32768 float4 per k-slice
        int rem = g & 32767;
        int n = rem >> 5;           // n = i*32+j
        int c4 = rem & 31;
        float4 v = *((const float4*)Wd + (size_t)(4 * n + k) * 32 + c4);
        ((ushort4*)(ws + WS_WD16))[g] = cvt4(v);
    } else {
        int s = g - 131072;         // [0, 12288)
        const float* src = (s < 4096) ? Wd1 : ((s < 8192) ? Wd2 : Wb);
        int r = s & 4095;
        float4 v = ((const float4*)src)[r];
        ((ushort4*)(ws + WS_SM16))[s] = cvt4(v);
    }
}

// ---------------------------------------------------------------------------
// Kernel 2: fused fp16 encoder GEMMs + K-step flow.
// 512 threads, __launch_bounds__(512,4): 64 arch + 64 acc regs (128 total)
// -> 16 waves/CU; LDS 79 KB -> 2 WGs/CU. Single-pass fp16 GEMM keeps
// per-wave arch demand ~55 regs (round-5 lesson: the 3-pass split needed
// ~95+ and memory-spilled at this cap). Each wave owns one 16-batch
// row-half (rh); fp16 W halves B-bytes so rh duplication costs nothing
// net vs round 3 (total L2 traffic back to ~2 GB).
// ---------------------------------------------------------------------------
__global__ __launch_bounds__(512, 4) void sylv_kernel(
    const ushort_t* __restrict__ wsb,
    const float* __restrict__ hglob,
    const float* __restrict__ z0,
    const float* __restrict__ bd,
    const float* __restrict__ bd1,
    const float* __restrict__ bd2,
    const float* __restrict__ bb,
    float* __restrict__ out)
{
    extern __shared__ char smem[];
    _Float16* Dh     = (_Float16*)(smem + SH_D_OFF);
    float*    sh_aux = (float*)(smem + SH_AUX_OFF);
    _Float16* sh_h   = (_Float16*)(smem + SH_H_OFF);
    float*    sh_z   = (float*)(smem + SH_Z_OFF);
    float*    sh_t   = (float*)(smem + SH_T_OFF);

    const int t   = threadIdx.x;
    const int bg0 = blockIdx.x * TB;
    const int lane = t & 63, w = t >> 6;
    const int l15 = lane & 15, l4 = lane >> 4;
    const int rh = w & 1;           // row-half (batches rh*16 .. rh*16+15)
    const int cg = w >> 1;          // column group (256 cols each)
    // flow mapping: 16 contiguous lanes (one quarter-wave) own one batch fb.
    const int j2 = t & 15;
    const int bq = (t >> 4) & 3;
    const int fb = (w & 1) | (bq << 1) | ((w >> 1) << 3);

    // ---- stage h (fp32 -> fp16 in LDS) and z0 ----
    {
        const float4* hsrc = (const float4*)(hglob + (size_t)bg0 * HDIM);
        #pragma unroll
        for (int it = 0; it < 2; ++it) {
            int c = t + it * 512;       // 1024 float4 chunks
            int row = c >> 5, col4 = c & 31;
            float4 v = hsrc[c];
            *(ushort4*)((ushort_t*)sh_h + row * 136 + col4 * 4) = cvt4(v);
        }
        int zb = t >> 4, zc = t & 15;
        float2 zv = *(const float2*)(z0 + (size_t)(bg0 + zb) * ZDIM + zc * 2);
        *(float2*)(sh_z + zb * 36 + zc * 2) = zv;
    }
    __syncthreads();

    // ---- A fragments for THIS wave's row-half: A[m=lane&15][k=quad*8+j] ----
    f16x8 ah[4];
    #pragma unroll
    for (int kc = 0; kc < 4; ++kc)
        ah[kc] = *(const f16x8*)(sh_h + (rh * 16 + l15) * 136 + kc * 32 + l4 * 8);

    // ---- small GEMMs (fp16): d1, d2, bpre -> aux[m][batch][n] ----
    // 24 p-jobs x 2 rh-waves = 48; each wave does 6 for its rh.
    #pragma unroll
    for (int pi = 0; pi < 6; ++pi) {
        int p = cg * 6 + pi;            // [0,24)
        int m_i = p >> 3, nt = p & 7, n = nt * 16 + l15;
        const _Float16* wp = (const _Float16*)(wsb + WS_SM16) + (size_t)(m_i * 128 + n) * 128 + l4 * 8;
        floatx4 a0 = {0.f, 0.f, 0.f, 0.f};
        #pragma unroll
        for (int kc = 0; kc < 4; ++kc) {
            f16x8 bh = *(const f16x8*)(wp + kc * 32);
            a0 = __builtin_amdgcn_mfma_f32_16x16x32_f16(ah[kc], bh, a0, 0, 0, 0);
        }
        const float* bv = (m_i == 0) ? bd1 : ((m_i == 1) ? bd2 : bb);
        float bias = bv[n];
        float* ap = sh_aux + m_i * (32 * AUX_PITCH) + n;
        #pragma unroll
        for (int r = 0; r < 4; ++r) {
            float v0 = a0[r] + bias;
            if (m_i < 2) v0 = fast_tanh(v0);
            ap[(rh * 16 + l4 * 4 + r) * AUX_PITCH] = v0;
        }
    }
    __syncthreads();

    // ---- aux -> registers (24 floats/thread), then free the D region ----
    float4 d1a = *(const float4*)(sh_aux + 0 * (32 * AUX_PITCH) + fb * AUX_PITCH + j2 * 4);
    float4 d2a = *(const float4*)(sh_aux + 1 * (32 * AUX_PITCH) + fb * AUX_PITCH + j2 * 4);
    float4 bpa = *(const float4*)(sh_aux + 2 * (32 * AUX_PITCH) + fb * AUX_PITCH + j2 * 4);
    float4 d1b = *(const float4*)(sh_aux + 0 * (32 * AUX_PITCH) + fb * AUX_PITCH + (j2 + 16) * 4);
    float4 d2b = *(const float4*)(sh_aux + 1 * (32 * AUX_PITCH) + fb * AUX_PITCH + (j2 + 16) * 4);
    float4 bpb = *(const float4*)(sh_aux + 2 * (32 * AUX_PITCH) + fb * AUX_PITCH + (j2 + 16) * 4);
    __syncthreads();

    float ld_acc = 0.f;
    const _Float16* Db  = Dh + fb * D_BP;
    const uint_t*   Dbw = (const uint_t*)Db;

    #pragma unroll
    for (int kk = 0; kk < KDIM; ++kk) {
        // ---- GEMM: D_k[b][n] = h@Wd_k^T + bd (fp16 inputs, fp32 acc) ----
        const _Float16* wdk = (const _Float16*)(wsb + WS_WD16) + (size_t)kk * 131072;
        #pragma unroll
        for (int g = 0; g < 8; ++g) {
            int nc0 = cg * 256 + g * 32 + l15;
            int nc1 = nc0 + 16;
            const _Float16* w0 = wdk + (size_t)nc0 * 128 + l4 * 8;
            const _Float16* w1 = w0 + 16 * 128;
            floatx4 a0 = {0.f,0.f,0.f,0.f}, a1 = {0.f,0.f,0.f,0.f};
            #pragma unroll
            for (int kc = 0; kc < 4; ++kc) {
                f16x8 b0 = *(const f16x8*)(w0 + kc * 32);
                a0 = __builtin_amdgcn_mfma_f32_16x16x32_f16(ah[kc], b0, a0, 0, 0, 0);
            }
            #pragma unroll
            for (int kc = 0; kc < 4; ++kc) {
                f16x8 b1 = *(const f16x8*)(w1 + kc * 32);
                a1 = __builtin_amdgcn_mfma_f32_16x16x32_f16(ah[kc], b1, a1, 0, 0, 0);
            }
            int ii = nc0 >> 5;
            int base0 = ii * D_ROW + (nc0 & 31);
            int base1 = base0 + 16;
            float bias0 = bd[4 * nc0 + kk];
            float bias1 = bd[4 * nc1 + kk];
            #pragma unroll
            for (int r = 0; r < 4; ++r) {
                Dh[(rh * 16 + l4 * 4 + r) * D_BP + base0] = (_Float16)(a0[r] + bias0);
                Dh[(rh * 16 + l4 * 4 + r) * D_BP + base1] = (_Float16)(a1[r] + bias1);
            }
        }
        __syncthreads();

        // ---- pre[j] = b[j] + z_per[j]*d2[j] + sum_{i>j} z_per[i]*D[i,j] ----
        const bool flip = (kk & 1) != 0;
        const int zj0 = flip ? (31 - j2) : j2;
        const int zj1 = flip ? (15 - j2) : (j2 + 16);
        float s0 = bpa[kk] + sh_z[fb * 36 + zj0] * d2a[kk];
        float s1 = bpb[kk] + sh_z[fb * 36 + zj1] * d2b[kk];
        #pragma unroll
        for (int i = 1; i <= 15; ++i) {       // masked vs j2
            float zi = sh_z[fb * 36 + (flip ? (31 - i) : i)];
            float dd = (float)Db[i * D_ROW + j2];
            s0 = fmaf(dd, (i > j2) ? zi : 0.f, s0);
        }
        #pragma unroll
        for (int i = 16; i < 32; ++i) {       // i > j2 always; s1 masked
            float zi = sh_z[fb * 36 + (flip ? (31 - i) : i)];
            s0 = fmaf((float)Db[i * D_ROW + j2], zi, s0);
            if (i >= 17)
                s1 = fmaf((float)Db[i * D_ROW + j2 + 16], (i > j2 + 16) ? zi : 0.f, s1);
        }
        float t0 = fast_tanh(s0), t1 = fast_tanh(s1);
        sh_t[fb * 36 + j2] = t0;
        sh_t[fb * 36 + j2 + 16] = t1;
        float dj0 = (1.f - t0 * t0) * (d1a[kk] * d2a[kk]) + 1.f;
        float dj1 = (1.f - t1 * t1) * (d1b[kk] * d2b[kk]) + 1.f;
        ld_acc += __logf(fabsf(dj0)) + __logf(fabsf(dj1));
        // no barrier: t/z exchange is within the 16-lane fb group (same wave)

        // ---- dz[p] = t[p]*d1[p] + sum_{j>p} t[j]*D[p,j]; z update ----
        float dz0 = t0 * d1a[kk];             // p = j2
        float dz1 = t1 * d1b[kk];             // p = j2+16
        const uint_t* r0 = Dbw + j2 * 17;     // D_ROW/2 words
        const uint_t* r1 = Dbw + (j2 + 16) * 17;
        #pragma unroll
        for (int w2 = 0; w2 < 8; ++w2) {      // j in [0,16): only dz0, masked
            uint_t v = r0[w2];
            int j0 = 2 * w2;
            float tl = sh_t[fb * 36 + j0];
            float th = sh_t[fb * 36 + j0 + 1];
            dz0 = fmaf(f16lo(v), (j0 > j2) ? tl : 0.f, dz0);
            dz0 = fmaf(f16hi(v), (j0 + 1 > j2) ? th : 0.f, dz0);
        }
        #pragma unroll
        for (int w2 = 8; w2 < 16; ++w2) {     // j in [16,32): dz0 unmasked, dz1 masked
            uint_t v0 = r0[w2];
            uint_t v1 = r1[w2];
            int j0 = 2 * w2;
            float tl = sh_t[fb * 36 + j0];
            float th = sh_t[fb * 36 + j0 + 1];
            dz0 = fmaf(f16lo(v0), tl, dz0);
            dz0 = fmaf(f16hi(v0), th, dz0);
            dz1 = fmaf(f16lo(v1), (j0 > j2 + 16) ? tl : 0.f, dz1);
            dz1 = fmaf(f16hi(v1), (j0 + 1 > j2 + 16) ? th : 0.f, dz1);
        }
        sh_z[fb * 36 + zj0] += dz0;
        sh_z[fb * 36 + zj1] += dz1;
        __syncthreads();
    }

    // ---- epilogue: write z and log_det_j ----
    {
        int zb = t >> 4, zc = t & 15;
        float2 zv = *(const float2*)(sh_z + zb * 36 + zc * 2);
        *(float2*)(out + (size_t)(bg0 + zb) * ZDIM + zc * 2) = zv;
        float v = ld_acc;
        v += __shfl_xor(v, 1, 16);
        v += __shfl_xor(v, 2, 16);
        v += __shfl_xor(v, 4, 16);
        v += __shfl_xor(v, 8, 16);
        if (j2 == 0) out[(size_t)B_TOTAL * ZDIM + bg0 + fb] = v;
    }
}

extern "C" void kernel_launch(void* const* d_in, const int* in_sizes, int n_in,
                              void* d_out, int out_size, void* d_ws, size_t ws_size,
                              hipStream_t stream) {
    const float* z0  = (const float*)d_in[0];
    const float* h   = (const float*)d_in[1];
    const float* Wd  = (const float*)d_in[2];
    const float* bd  = (const float*)d_in[3];
    const float* Wd1 = (const float*)d_in[4];
    const float* bd1 = (const float*)d_in[5];
    const float* Wd2 = (const float*)d_in[6];
    const float* bd2 = (const float*)d_in[7];
    const float* Wb  = (const float*)d_in[8];
    const float* bb  = (const float*)d_in[9];
    ushort_t* ws = (ushort_t*)d_ws;
    float* out = (float*)d_out;

    convert_kernel<<<560, 256, 0, stream>>>(Wd, Wd1, Wd2, Wb, ws);

    (void)hipFuncSetAttribute((const void*)sylv_kernel,
                              hipFuncAttributeMaxDynamicSharedMemorySize, LDS_BYTES);
    sylv_kernel<<<B_TOTAL / TB, 512, LDS_BYTES, stream>>>(ws, h, z0, bd, bd1, bd2, bb, out);
}

// Round 8
// 370.821 us; speedup vs baseline: 1.7393x; 1.0125x over previous
//
#include <hip/hip_runtime.h>

typedef unsigned short ushort_t;
typedef unsigned int uint_t;
typedef __attribute__((ext_vector_type(8))) _Float16 f16x8;
typedef __attribute__((ext_vector_type(4))) float floatx4;

#define ZDIM 32
#define KDIM 4
#define HDIM 128
#define B_TOTAL 32768
#define TB 32

// ws layout (ushort element offsets): Wd fp16 [k][n][c], Wsm fp16 [m][n][c]
#define WS_WD16 0            // 4*1024*128 = 524288
#define WS_SM16 524288       // 3*128*128 = 49152

// LDS layout (byte offsets). D is fp16: [batch][i][j] at batch*1092 + i*34 + j
// (ushort units).
#define D_ROW   34
#define D_BP    1092
#define SH_D_OFF  0          // ushort[32][1092] = 69888 B
#define AUX_PITCH 132
#define SH_AUX_OFF 0         // float [3][32][132] = 50688 B (pre-loop, aliases D)
#define SH_H_OFF  50688      // half [32][136] = 8704 B (pre-loop, aliases D)
#define SH_Z_OFF  69888      // float [32][36] = 4608 B
#define SH_T_OFF  74496      // float [32][36] = 4608 B
#define LDS_BYTES 79104      // x2 = 158208 <= 160 KiB -> 2 WG/CU via LDS

__device__ __forceinline__ float fast_tanh(float x) {
    float e = __expf(2.0f * x);
    return 1.0f - 2.0f / (e + 1.0f);
}
__device__ __forceinline__ float f16lo(uint_t v) {
    return (float)__builtin_bit_cast(_Float16, (ushort_t)(v & 0xFFFFu));
}
__device__ __forceinline__ float f16hi(uint_t v) {
    return (float)__builtin_bit_cast(_Float16, (ushort_t)(v >> 16));
}
__device__ __forceinline__ ushort_t f2h(float x) {
    return __builtin_bit_cast(ushort_t, (_Float16)x);
}
__device__ __forceinline__ ushort4 cvt4(float4 v) {
    ushort4 o; o.x = f2h(v.x); o.y = f2h(v.y); o.z = f2h(v.z); o.w = f2h(v.w);
    return o;
}
// pack 4 floats into 2 dwords of fp16 (register-pressure relief; kk index
// folds at compile time under full unroll)
__device__ __forceinline__ uint2 packq(float4 v) {
    uint2 r;
    r.x = (uint_t)f2h(v.x) | ((uint_t)f2h(v.y) << 16);
    r.y = (uint_t)f2h(v.z) | ((uint_t)f2h(v.w) << 16);
    return r;
}
__device__ __forceinline__ float half_at(uint2 q, int kk) {
    uint_t w = (kk & 2) ? q.y : q.x;
    return (kk & 1) ? f16hi(w) : f16lo(w);
}

// ---------------------------------------------------------------------------
// Kernel 1: convert Wd (reordered per-k-slice) and Wd1/Wd2/Wb to fp16.
// ---------------------------------------------------------------------------
__global__ __launch_bounds__(256) void convert_kernel(
    const float* __restrict__ Wd, const float* __restrict__ Wd1,
    const float* __restrict__ Wd2, const float* __restrict__ Wb,
    ushort_t* __restrict__ ws)
{
    int g = blockIdx.x * 256 + threadIdx.x;
    if (g < 131072) {
        int k = g >> 15;            // 32768 float4 per k-slice
        int rem = g & 32767;
        int n = rem >> 5;           // n = i*32+j
        int c4 = rem & 31;
        float4 v = *((const float4*)Wd + (size_t)(4 * n + k) * 32 + c4);
        ((ushort4*)(ws + WS_WD16))[g] = cvt4(v);
    } else {
        int s = g - 131072;         // [0, 12288)
        const float* src = (s < 4096) ? Wd1 : ((s < 8192) ? Wd2 : Wb);
        int r = s & 4095;
        float4 v = ((const float4*)src)[r];
        ((ushort4*)(ws + WS_SM16))[s] = cvt4(v);
    }
}

// ---------------------------------------------------------------------------
// Kernel 2: fused fp16 encoder GEMMs + K-step flow.
// 512 threads, __launch_bounds__(512,4): 64 arch + 64 acc regs (128 total)
// -> 4 waves/SIMD -> 2 WGs/CU (LDS 79 KB also allows exactly 2).
// Round-8 change: aux (d1/d2/bp, 24 floats) lives as 12 packed-fp16 dwords,
// cutting peak arch demand ~71 -> ~59 <= 64 so the k-loop runs with ZERO
// scratch spill (round-7: ~112 MB spill writes dominated latency).
// ---------------------------------------------------------------------------
__global__ __launch_bounds__(512, 4) void sylv_kernel(
    const ushort_t* __restrict__ wsb,
    const float* __restrict__ hglob,
    const float* __restrict__ z0,
    const float* __restrict__ bd,
    const float* __restrict__ bd1,
    const float* __restrict__ bd2,
    const float* __restrict__ bb,
    float* __restrict__ out)
{
    extern __shared__ char smem[];
    _Float16* Dh     = (_Float16*)(smem + SH_D_OFF);
    float*    sh_aux = (float*)(smem + SH_AUX_OFF);
    _Float16* sh_h   = (_Float16*)(smem + SH_H_OFF);
    float*    sh_z   = (float*)(smem + SH_Z_OFF);
    float*    sh_t   = (float*)(smem + SH_T_OFF);

    const int t   = threadIdx.x;
    const int bg0 = blockIdx.x * TB;
    const int lane = t & 63, w = t >> 6;
    const int l15 = lane & 15, l4 = lane >> 4;
    const int rh = w & 1;           // row-half (batches rh*16 .. rh*16+15)
    const int cg = w >> 1;          // column group (256 cols each)
    // flow mapping: 16 contiguous lanes (one quarter-wave) own one batch fb.
    const int j2 = t & 15;
    const int bq = (t >> 4) & 3;
    const int fb = (w & 1) | (bq << 1) | ((w >> 1) << 3);

    // ---- stage h (fp32 -> fp16 in LDS) and z0 ----
    {
        const float4* hsrc = (const float4*)(hglob + (size_t)bg0 * HDIM);
        #pragma unroll
        for (int it = 0; it < 2; ++it) {
            int c = t + it * 512;       // 1024 float4 chunks
            int row = c >> 5, col4 = c & 31;
            float4 v = hsrc[c];
            *(ushort4*)((ushort_t*)sh_h + row * 136 + col4 * 4) = cvt4(v);
        }
        int zb = t >> 4, zc = t & 15;
        float2 zv = *(const float2*)(z0 + (size_t)(bg0 + zb) * ZDIM + zc * 2);
        *(float2*)(sh_z + zb * 36 + zc * 2) = zv;
    }
    __syncthreads();

    // ---- A fragments for THIS wave's row-half: A[m=lane&15][k=quad*8+j] ----
    f16x8 ah[4];
    #pragma unroll
    for (int kc = 0; kc < 4; ++kc)
        ah[kc] = *(const f16x8*)(sh_h + (rh * 16 + l15) * 136 + kc * 32 + l4 * 8);

    // ---- small GEMMs (fp16): d1, d2, bpre -> aux[m][batch][n] ----
    // 24 p-jobs x 2 rh-waves = 48; each wave does 6 for its rh.
    #pragma unroll
    for (int pi = 0; pi < 6; ++pi) {
        int p = cg * 6 + pi;            // [0,24)
        int m_i = p >> 3, nt = p & 7, n = nt * 16 + l15;
        const _Float16* wp = (const _Float16*)(wsb + WS_SM16) + (size_t)(m_i * 128 + n) * 128 + l4 * 8;
        floatx4 a0 = {0.f, 0.f, 0.f, 0.f};
        #pragma unroll
        for (int kc = 0; kc < 4; ++kc) {
            f16x8 bh = *(const f16x8*)(wp + kc * 32);
            a0 = __builtin_amdgcn_mfma_f32_16x16x32_f16(ah[kc], bh, a0, 0, 0, 0);
        }
        const float* bv = (m_i == 0) ? bd1 : ((m_i == 1) ? bd2 : bb);
        float bias = bv[n];
        float* ap = sh_aux + m_i * (32 * AUX_PITCH) + n;
        #pragma unroll
        for (int r = 0; r < 4; ++r) {
            float v0 = a0[r] + bias;
            if (m_i < 2) v0 = fast_tanh(v0);
            ap[(rh * 16 + l4 * 4 + r) * AUX_PITCH] = v0;
        }
    }
    __syncthreads();

    // ---- aux -> 12 packed-fp16 dwords/thread, then free the D region ----
    uint2 d1a = packq(*(const float4*)(sh_aux + 0 * (32 * AUX_PITCH) + fb * AUX_PITCH + j2 * 4));
    uint2 d2a = packq(*(const float4*)(sh_aux + 1 * (32 * AUX_PITCH) + fb * AUX_PITCH + j2 * 4));
    uint2 bpa = packq(*(const float4*)(sh_aux + 2 * (32 * AUX_PITCH) + fb * AUX_PITCH + j2 * 4));
    uint2 d1b = packq(*(const float4*)(sh_aux + 0 * (32 * AUX_PITCH) + fb * AUX_PITCH + (j2 + 16) * 4));
    uint2 d2b = packq(*(const float4*)(sh_aux + 1 * (32 * AUX_PITCH) + fb * AUX_PITCH + (j2 + 16) * 4));
    uint2 bpb = packq(*(const float4*)(sh_aux + 2 * (32 * AUX_PITCH) + fb * AUX_PITCH + (j2 + 16) * 4));
    __syncthreads();

    float ld_acc = 0.f;
    const _Float16* Db  = Dh + fb * D_BP;

    #pragma unroll
    for (int kk = 0; kk < KDIM; ++kk) {
        // ---- GEMM: D_k[b][n] = h@Wd_k^T + bd (fp16 inputs, fp32 acc) ----
        const _Float16* wdk = (const _Float16*)(wsb + WS_WD16) + (size_t)kk * 131072;
        #pragma unroll
        for (int g = 0; g < 8; ++g) {
            int nc0 = cg * 256 + g * 32 + l15;
            int nc1 = nc0 + 16;
            const _Float16* w0 = wdk + (size_t)nc0 * 128 + l4 * 8;
            const _Float16* w1 = w0 + 16 * 128;
            floatx4 a0 = {0.f,0.f,0.f,0.f}, a1 = {0.f,0.f,0.f,0.f};
            #pragma unroll
            for (int kc = 0; kc < 4; ++kc) {
                f16x8 b0 = *(const f16x8*)(w0 + kc * 32);
                a0 = __builtin_amdgcn_mfma_f32_16x16x32_f16(ah[kc], b0, a0, 0, 0, 0);
            }
            #pragma unroll
            for (int kc = 0; kc < 4; ++kc) {
                f16x8 b1 = *(const f16x8*)(w1 + kc * 32);
                a1 = __builtin_amdgcn_mfma_f32_16x16x32_f16(ah[kc], b1, a1, 0, 0, 0);
            }
            int ii = nc0 >> 5;
            int base0 = ii * D_ROW + (nc0 & 31);
            int base1 = base0 + 16;
            float bias0 = bd[4 * nc0 + kk];
            float bias1 = bd[4 * nc1 + kk];
            #pragma unroll
            for (int r = 0; r < 4; ++r) {
                Dh[(rh * 16 + l4 * 4 + r) * D_BP + base0] = (_Float16)(a0[r] + bias0);
                Dh[(rh * 16 + l4 * 4 + r) * D_BP + base1] = (_Float16)(a1[r] + bias1);
            }
        }
        __syncthreads();

        // ---- pre[j] = b[j] + z_per[j]*d2[j] + sum_{i>j} z_per[i]*D[i,j] ----
        const bool flip = (kk & 1) != 0;
        const int zj0 = flip ? (31 - j2) : j2;
        const int zj1 = flip ? (15 - j2) : (j2 + 16);
        float s0 = half_at(bpa, kk) + sh_z[fb * 36 + zj0] * half_at(d2a, kk);
        float s1 = half_at(bpb, kk) + sh_z[fb * 36 + zj1] * half_at(d2b, kk);
        #pragma unroll
        for (int i = 1; i <= 15; ++i) {       // masked vs j2
            float zi = sh_z[fb * 36 + (flip ? (31 - i) : i)];
            float dd = (float)Db[i * D_ROW + j2];
            s0 = fmaf(dd, (i > j2) ? zi : 0.f, s0);
        }
        #pragma unroll
        for (int i = 16; i < 32; ++i) {       // i > j2 always; s1 masked
            float zi = sh_z[fb * 36 + (flip ? (31 - i) : i)];
            s0 = fmaf((float)Db[i * D_ROW + j2], zi, s0);
            if (i >= 17)
                s1 = fmaf((float)Db[i * D_ROW + j2 + 16], (i > j2 + 16) ? zi : 0.f, s1);
        }
        float t0 = fast_tanh(s0), t1 = fast_tanh(s1);
        sh_t[fb * 36 + j2] = t0;
        sh_t[fb * 36 + j2 + 16] = t1;
        float dj0 = (1.f - t0 * t0) * (half_at(d1a, kk) * half_at(d2a, kk)) + 1.f;
        float dj1 = (1.f - t1 * t1) * (half_at(d1b, kk) * half_at(d2b, kk)) + 1.f;
        ld_acc += __logf(fabsf(dj0)) + __logf(fabsf(dj1));
        // no barrier: t/z exchange is within the 16-lane fb group (same wave)

        // ---- dz[p] = t[p]*d1[p] + sum_{j>p} t[j]*D[p,j]; z update ----
        float dz0 = t0 * half_at(d1a, kk);    // p = j2
        float dz1 = t1 * half_at(d1b, kk);    // p = j2+16
        const uint_t* r0 = (const uint_t*)Db + j2 * 17;     // D_ROW/2 words
        const uint_t* r1 = (const uint_t*)Db + (j2 + 16) * 17;
        #pragma unroll
        for (int w2 = 0; w2 < 8; ++w2) {      // j in [0,16): only dz0, masked
            uint_t v = r0[w2];
            int j0 = 2 * w2;
            float tl = sh_t[fb * 36 + j0];
            float th = sh_t[fb * 36 + j0 + 1];
            dz0 = fmaf(f16lo(v), (j0 > j2) ? tl : 0.f, dz0);
            dz0 = fmaf(f16hi(v), (j0 + 1 > j2) ? th : 0.f, dz0);
        }
        #pragma unroll
        for (int w2 = 8; w2 < 16; ++w2) {     // j in [16,32): dz0 unmasked, dz1 masked
            uint_t v0 = r0[w2];
            uint_t v1 = r1[w2];
            int j0 = 2 * w2;
            float tl = sh_t[fb * 36 + j0];
            float th = sh_t[fb * 36 + j0 + 1];
            dz0 = fmaf(f16lo(v0), tl, dz0);
            dz0 = fmaf(f16hi(v0), th, dz0);
            dz1 = fmaf(f16lo(v1), (j0 > j2 + 16) ? tl : 0.f, dz1);
            dz1 = fmaf(f16hi(v1), (j0 + 1 > j2 + 16) ? th : 0.f, dz1);
        }
        sh_z[fb * 36 + zj0] += dz0;
        sh_z[fb * 36 + zj1] += dz1;
        __syncthreads();
    }

    // ---- epilogue: write z and log_det_j ----
    {
        int zb = t >> 4, zc = t & 15;
        float2 zv = *(const float2*)(sh_z + zb * 36 + zc * 2);
        *(float2*)(out + (size_t)(bg0 + zb) * ZDIM + zc * 2) = zv;
        float v = ld_acc;
        v += __shfl_xor(v, 1, 16);
        v += __shfl_xor(v, 2, 16);
        v += __shfl_xor(v, 4, 16);
        v += __shfl_xor(v, 8, 16);
        if (j2 == 0) out[(size_t)B_TOTAL * ZDIM + bg0 + fb] = v;
    }
}

extern "C" void kernel_launch(void* const* d_in, const int* in_sizes, int n_in,
                              void* d_out, int out_size, void* d_ws, size_t ws_size,
                              hipStream_t stream) {
    const float* z0  = (const float*)d_in[0];
    const float* h   = (const float*)d_in[1];
    const float* Wd  = (const float*)d_in[2];
    const float* bd  = (const float*)d_in[3];
    const float* Wd1 = (const float*)d_in[4];
    const float* bd1 = (const float*)d_in[5];
    const float* Wd2 = (const float*)d_in[6];
    const float* bd2 = (const float*)d_in[7];
    const float* Wb  = (const float*)d_in[8];
    const float* bb  = (const float*)d_in[9];
    ushort_t* ws = (ushort_t*)d_ws;
    float* out = (float*)d_out;

    convert_kernel<<<560, 256, 0, stream>>>(Wd, Wd1, Wd2, Wb, ws);

    (void)hipFuncSetAttribute((const void*)sylv_kernel,
                              hipFuncAttributeMaxDynamicSharedMemorySize, LDS_BYTES);
    sylv_kernel<<<B_TOTAL / TB, 512, LDS_BYTES, stream>>>(ws, h, z0, bd, bd1, bd2, bb, out);
}